// Round 1
// baseline (118.351 us; speedup 1.0000x reference)
//
#include <hip/hip_runtime.h>
#include <hip/hip_bf16.h>

#define N 384
#define D 128
#define NT 24            // N/16
#define TAU 0.25f
#define MARGIN 0.5f

// ---------------- K1: L2-normalize rows of both matrices ----------------
// grid: 2*N blocks of 64 threads; block b<N -> src row b, else emb row b-N
__global__ __launch_bounds__(64) void k_norm(const float* __restrict__ src,
                                             const float* __restrict__ emb,
                                             float* __restrict__ xn_src,
                                             float* __restrict__ xn_emb) {
    int b = blockIdx.x;
    const float* x;
    float* y;
    int row;
    if (b < N) { x = src; y = xn_src; row = b; }
    else       { x = emb; y = xn_emb; row = b - N; }
    int lane = threadIdx.x;               // 0..63, D/2=64 float2 per row
    float2 v = ((const float2*)(x + (size_t)row * D))[lane];
    float ss = v.x * v.x + v.y * v.y;
    #pragma unroll
    for (int o = 32; o > 0; o >>= 1) ss += __shfl_xor(ss, o);
    float nrm = sqrtf(ss);
    float inv = 1.0f / fmaxf(nrm, 1e-12f);
    float2 o2 = {v.x * inv, v.y * inv};
    ((float2*)(y + (size_t)row * D))[lane] = o2;
}

// ---------------- K2: Gram -> distance matrices, plus sum(d_src) --------
// grid: 2*NT*NT blocks of (16,16). mat 0 = src (also accumulates sum), 1 = emb.
__global__ __launch_bounds__(256) void k_gram(const float* __restrict__ xn_src,
                                              const float* __restrict__ xn_emb,
                                              float* __restrict__ s_src,
                                              float* __restrict__ s_emb,
                                              float* __restrict__ accum) {
    __shared__ float A[16][17], B[16][17];
    __shared__ float part[4];
    int bid = blockIdx.x;
    int mat = bid / (NT * NT);
    int t2  = bid % (NT * NT);
    int bi = t2 / NT, bj = t2 % NT;
    const float* xn = (mat == 0) ? xn_src : xn_emb;
    float* out      = (mat == 0) ? s_src : s_emb;
    int tx = threadIdx.x, ty = threadIdx.y;
    float acc = 0.0f;
    for (int kk = 0; kk < D; kk += 16) {
        A[ty][tx] = xn[(size_t)(bi * 16 + ty) * D + kk + tx];
        B[ty][tx] = xn[(size_t)(bj * 16 + ty) * D + kk + tx];
        __syncthreads();
        #pragma unroll
        for (int k = 0; k < 16; k++) acc += A[ty][k] * B[tx][k];
        __syncthreads();
    }
    float dist = 1.0f - acc;
    out[(size_t)(bi * 16 + ty) * N + bj * 16 + tx] = dist;
    if (mat == 0) {
        float s = dist;
        #pragma unroll
        for (int o = 32; o > 0; o >>= 1) s += __shfl_xor(s, o);
        int tid = ty * 16 + tx;
        if ((tid & 63) == 0) part[tid >> 6] = s;
        __syncthreads();
        if (tid == 0) atomicAdd(&accum[0], part[0] + part[1] + part[2] + part[3]);
    }
}

// ---------------- K3: w_pos = exp(-(d/mean)/tau), in place --------------
__global__ __launch_bounds__(256) void k_weights(float* __restrict__ wsrc,
                                                 const float* __restrict__ accum) {
    float mean  = accum[0] * (1.0f / (float)(N * N));
    float scale = 1.0f / (fmaxf(mean, 1e-12f) * TAU);
    int idx = blockIdx.x * blockDim.x + threadIdx.x;
    if (idx < N * N) wsrc[idx] = expf(-wsrc[idx] * scale);
}

// ---------------- K4: per-(i,j) semihard max over k, fused reduction ----
// grid: N blocks of N threads. Row i data staged in LDS.
__global__ __launch_bounds__(N) void k_main(const float* __restrict__ wsrc,
                                            const float* __restrict__ demb,
                                            float* __restrict__ accum) {
    __shared__ float de[N];
    __shared__ float wn[N];
    __shared__ float wp[N];
    __shared__ float pn[6], pd[6];
    int i = blockIdx.x;
    int t = threadIdx.x;
    de[t] = demb[(size_t)i * N + t];
    float w = wsrc[(size_t)i * N + t];
    wp[t] = w;
    wn[t] = 1.0f - w;
    __syncthreads();
    float c = MARGIN + de[t];     // t_l = c - de[k]
    float m = 0.0f;
    #pragma unroll 4
    for (int k = 0; k < N; k++) {
        float tl = c - de[k];
        float v  = (tl > 0.0f && tl <= MARGIN) ? tl * wn[k] : 0.0f;
        m = fmaxf(m, v);
    }
    float wpij = wp[t];
    float numc = wpij * wpij * m;
    float denc = wpij;
    #pragma unroll
    for (int o = 32; o > 0; o >>= 1) {
        numc += __shfl_xor(numc, o);
        denc += __shfl_xor(denc, o);
    }
    if ((t & 63) == 0) { pn[t >> 6] = numc; pd[t >> 6] = denc; }
    __syncthreads();
    if (t == 0) {
        float sn = 0.0f, sd = 0.0f;
        #pragma unroll
        for (int wv = 0; wv < 6; wv++) { sn += pn[wv]; sd += pd[wv]; }
        atomicAdd(&accum[1], sn);
        atomicAdd(&accum[2], sd);
    }
}

// ---------------- K5: final safe division -------------------------------
__global__ void k_final(const float* __restrict__ accum, float* __restrict__ out) {
    float num = accum[1], den = accum[2];
    out[0] = (den > 0.0f) ? num / den : 0.0f;
}

extern "C" void kernel_launch(void* const* d_in, const int* in_sizes, int n_in,
                              void* d_out, int out_size, void* d_ws, size_t ws_size,
                              hipStream_t stream) {
    const float* src = (const float*)d_in[0];
    const float* emb = (const float*)d_in[1];
    float* out = (float*)d_out;

    float* ws = (float*)d_ws;
    float* xn_src = ws;                          // N*D
    float* xn_emb = xn_src + N * D;              // N*D
    float* wsrc   = xn_emb + N * D;              // N*N (dist -> w_pos in place)
    float* demb   = wsrc + N * N;                // N*N
    float* accum  = demb + N * N;                // [0]=sum_dist [1]=num [2]=den

    hipMemsetAsync(accum, 0, 4 * sizeof(float), stream);

    k_norm<<<2 * N, 64, 0, stream>>>(src, emb, xn_src, xn_emb);
    k_gram<<<2 * NT * NT, dim3(16, 16), 0, stream>>>(xn_src, xn_emb, wsrc, demb, accum);
    k_weights<<<(N * N + 255) / 256, 256, 0, stream>>>(wsrc, accum);
    k_main<<<N, N, 0, stream>>>(wsrc, demb, accum);
    k_final<<<1, 1, 0, stream>>>(accum, out);
}

// Round 2
// 87.282 us; speedup vs baseline: 1.3560x; 1.3560x over previous
//
#include <hip/hip_runtime.h>
#include <hip/hip_bf16.h>

#define N 384
#define D 128
#define TAU 0.25f
#define MARGIN 0.5f

// ---------------- K1: L2-normalize rows of both matrices; zero accum ----
// grid: 2*N blocks of 64 threads; block b<N -> src row b, else emb row b-N
__global__ __launch_bounds__(64) void k_norm(const float* __restrict__ src,
                                             const float* __restrict__ emb,
                                             float* __restrict__ xn_src,
                                             float* __restrict__ xn_emb,
                                             float* __restrict__ accum) {
    int b = blockIdx.x;
    int lane = threadIdx.x;               // 0..63, D/2=64 float2 per row
    if (b == 0 && lane == 0) { accum[0] = 0.f; accum[1] = 0.f; accum[2] = 0.f; }
    const float* x;
    float* y;
    int row;
    if (b < N) { x = src; y = xn_src; row = b; }
    else       { x = emb; y = xn_emb; row = b - N; }
    float2 v = ((const float2*)(x + (size_t)row * D))[lane];
    float ss = v.x * v.x + v.y * v.y;
    #pragma unroll
    for (int o = 32; o > 0; o >>= 1) ss += __shfl_xor(ss, o);
    float inv = 1.0f / fmaxf(sqrtf(ss), 1e-12f);
    float2 o2 = {v.x * inv, v.y * inv};
    ((float2*)(y + (size_t)row * D))[lane] = o2;
}

// ---------------- K2: Gram -> distance matrices, plus sum(d_src) --------
// grid: 2*144 blocks of 256 threads; each block one 32x32 output tile.
// Full K=128 staged once in transposed LDS; 2x2 micro-tile per thread.
__global__ __launch_bounds__(256) void k_gram(const float* __restrict__ xn_src,
                                              const float* __restrict__ xn_emb,
                                              float* __restrict__ dsrc,
                                              float* __restrict__ demb,
                                              float* __restrict__ accum) {
    __shared__ float At[D][34];
    __shared__ float Bt[D][34];
    __shared__ float ps[4];
    int bid = blockIdx.x;
    int mat = (bid >= 144) ? 1 : 0;
    int t2  = mat ? bid - 144 : bid;
    int bi = t2 / 12, bj = t2 % 12;
    const float* xn = mat ? xn_emb : xn_src;
    float* out      = mat ? demb : dsrc;
    int lin = threadIdx.x;
    #pragma unroll
    for (int l = 0; l < 4; l++) {
        int idx = lin + l * 256;
        int row = idx >> 5;       // 0..31
        int c4  = idx & 31;       // 0..31 (float4 index within row)
        float4 va = ((const float4*)(xn + (size_t)(bi * 32 + row) * D))[c4];
        At[c4 * 4 + 0][row] = va.x; At[c4 * 4 + 1][row] = va.y;
        At[c4 * 4 + 2][row] = va.z; At[c4 * 4 + 3][row] = va.w;
        float4 vb = ((const float4*)(xn + (size_t)(bj * 32 + row) * D))[c4];
        Bt[c4 * 4 + 0][row] = vb.x; Bt[c4 * 4 + 1][row] = vb.y;
        Bt[c4 * 4 + 2][row] = vb.z; Bt[c4 * 4 + 3][row] = vb.w;
    }
    __syncthreads();
    int tx = lin & 15, ty = lin >> 4;
    float a00 = 0.f, a01 = 0.f, a10 = 0.f, a11 = 0.f;
    #pragma unroll 8
    for (int k = 0; k < D; k++) {
        float x0 = At[k][2 * ty], x1 = At[k][2 * ty + 1];
        float y0 = Bt[k][2 * tx], y1 = Bt[k][2 * tx + 1];
        a00 = fmaf(x0, y0, a00); a01 = fmaf(x0, y1, a01);
        a10 = fmaf(x1, y0, a10); a11 = fmaf(x1, y1, a11);
    }
    float d00 = 1.f - a00, d01 = 1.f - a01, d10 = 1.f - a10, d11 = 1.f - a11;
    int r0 = bi * 32 + 2 * ty, c0 = bj * 32 + 2 * tx;
    out[(size_t)r0 * N + c0]           = d00;
    out[(size_t)r0 * N + c0 + 1]       = d01;
    out[(size_t)(r0 + 1) * N + c0]     = d10;
    out[(size_t)(r0 + 1) * N + c0 + 1] = d11;
    if (!mat) {
        float s = d00 + d01 + d10 + d11;
        #pragma unroll
        for (int o = 32; o > 0; o >>= 1) s += __shfl_xor(s, o);
        if ((lin & 63) == 0) ps[lin >> 6] = s;
        __syncthreads();
        if (lin == 0) atomicAdd(&accum[0], ps[0] + ps[1] + ps[2] + ps[3]);
    }
}

// ---------------- K3: wp = exp(-(d/mean)/tau), in place over dsrc -------
__global__ __launch_bounds__(256) void k_weights(float* __restrict__ wsrc,
                                                 const float* __restrict__ accum) {
    float mean  = accum[0] * (1.0f / (float)(N * N));
    float scale = 1.0f / (fmaxf(mean, 1e-12f) * TAU);
    int idx = blockIdx.x * 256 + threadIdx.x;
    wsrc[idx] = expf(-wsrc[idx] * scale);
}

// ---------------- K4: per-(i,j) semihard max over k, fused reduction ----
// grid: N blocks of N threads. k-streams read via UNIFORM loads (-> SGPR),
// so the inner loop is pure VALU: 6 ops/iter, 4 independent max accums.
__global__ __launch_bounds__(N) void k_main(const float* __restrict__ wp,
                                            const float* __restrict__ de,
                                            float* __restrict__ accum) {
    __shared__ float pn[6], pd[6];
    int i = blockIdx.x;
    int t = threadIdx.x;
    const float* der = de + (size_t)i * N;   // emb distance row i
    const float* wpr = wp + (size_t)i * N;   // teacher pos-weight row i
    float q = der[t];
    float c = MARGIN + q;                    // tl = c - de[k]
    float m0 = 0.f, m1 = 0.f, m2 = 0.f, m3 = 0.f;
    #pragma unroll 2
    for (int k = 0; k < N; k += 4) {
        float dk0 = der[k], dk1 = der[k + 1], dk2 = der[k + 2], dk3 = der[k + 3];
        float wk0 = wpr[k], wk1 = wpr[k + 1], wk2 = wpr[k + 2], wk3 = wpr[k + 3];
        float tl0 = c - dk0; float v0 = tl0 * (1.f - wk0);
        v0 = (tl0 <= MARGIN) ? v0 : 0.f; m0 = fmaxf(m0, v0);
        float tl1 = c - dk1; float v1 = tl1 * (1.f - wk1);
        v1 = (tl1 <= MARGIN) ? v1 : 0.f; m1 = fmaxf(m1, v1);
        float tl2 = c - dk2; float v2 = tl2 * (1.f - wk2);
        v2 = (tl2 <= MARGIN) ? v2 : 0.f; m2 = fmaxf(m2, v2);
        float tl3 = c - dk3; float v3 = tl3 * (1.f - wk3);
        v3 = (tl3 <= MARGIN) ? v3 : 0.f; m3 = fmaxf(m3, v3);
    }
    float m = fmaxf(fmaxf(m0, m1), fmaxf(m2, m3));
    float w = wpr[t];
    float numc = w * w * m;
    float denc = w;
    #pragma unroll
    for (int o = 32; o > 0; o >>= 1) {
        numc += __shfl_xor(numc, o);
        denc += __shfl_xor(denc, o);
    }
    if ((t & 63) == 0) { pn[t >> 6] = numc; pd[t >> 6] = denc; }
    __syncthreads();
    if (t == 0) {
        float sn = 0.f, sd = 0.f;
        #pragma unroll
        for (int wv = 0; wv < 6; wv++) { sn += pn[wv]; sd += pd[wv]; }
        atomicAdd(&accum[1], sn);
        atomicAdd(&accum[2], sd);
    }
}

// ---------------- K5: final safe division -------------------------------
__global__ void k_final(const float* __restrict__ accum, float* __restrict__ out) {
    float num = accum[1], den = accum[2];
    out[0] = (den > 0.0f) ? num / den : 0.0f;
}

extern "C" void kernel_launch(void* const* d_in, const int* in_sizes, int n_in,
                              void* d_out, int out_size, void* d_ws, size_t ws_size,
                              hipStream_t stream) {
    const float* src = (const float*)d_in[0];
    const float* emb = (const float*)d_in[1];
    float* out = (float*)d_out;

    float* ws = (float*)d_ws;
    float* xn_src = ws;                          // N*D
    float* xn_emb = xn_src + N * D;              // N*D
    float* wsrc   = xn_emb + N * D;              // N*N (dist -> w_pos in place)
    float* demb   = wsrc + N * N;                // N*N
    float* accum  = demb + N * N;                // [0]=sum_dist [1]=num [2]=den

    k_norm<<<2 * N, 64, 0, stream>>>(src, emb, xn_src, xn_emb, accum);
    k_gram<<<2 * 144, 256, 0, stream>>>(xn_src, xn_emb, wsrc, demb, accum);
    k_weights<<<(N * N) / 256, 256, 0, stream>>>(wsrc, accum);
    k_main<<<N, N, 0, stream>>>(wsrc, demb, accum);
    k_final<<<1, 1, 0, stream>>>(accum, out);
}